// Round 8
// baseline (292.133 us; speedup 1.0000x reference)
//
#include <hip/hip_runtime.h>

#define DIN   128
#define DSL   64
#define KSL   11
#define NTOK  4096
#define NB    64
#define NSPLIT 32
#define LN_EPS   1e-5f
#define ATTN_EPS 1e-8f
#define SCALE    0.125f      // 64^-0.5

typedef __bf16 bf16x8 __attribute__((ext_vector_type(8)));
typedef float  f32x4  __attribute__((ext_vector_type(4)));

// ---------------------------------------------------------------------------
// Kernel 0 (9 blocks): blocks 0..7 pre-gather W' = diag(g)·[Wk|Wv] into MFMA
// A-fragment order; block 8: EP[c] = sum_k g[k]W[k][c], EP[128+c] = b@W.
// ---------------------------------------------------------------------------
__global__ void k_prep(const float* __restrict__ Wk, const float* __restrict__ Wv,
                       const float* __restrict__ g, const float* __restrict__ b,
                       __bf16* __restrict__ WTf, float* __restrict__ EP) {
  if (blockIdx.x == 8) {
    const int c = threadIdx.x;
    if (c < 128) {
      const float* __restrict__ W = (c < 64) ? Wk : Wv;
      const int cc = c & 63;
      float G = 0.f, Bt = 0.f;
      for (int k = 0; k < 128; ++k) {
        const float w = W[k * 64 + cc];
        G += g[k] * w; Bt += b[k] * w;
      }
      EP[c] = G; EP[128 + c] = Bt;
    }
    return;
  }
  const int t = blockIdx.x * 256 + threadIdx.x;
  const int fid = t >> 6, lane = t & 63;
  const int ks = fid >> 3, nt = fid & 7;
  const int col = nt * 16 + (lane & 15);
  const int kb  = ks * 32 + (lane >> 4) * 8;
  union { uint4 u; __bf16 h[8]; } o;
#pragma unroll
  for (int j = 0; j < 8; ++j) {
    const int k = kb + j;
    const float v = ((col < 64) ? Wk[k * 64 + col] : Wv[k * 64 + (col - 64)]) * g[k];
    o.h[j] = (__bf16)v;
  }
  *((uint4*)WTf + t) = o.u;
}

// ===========================================================================
// ABLATION VARIANT A: no stats / no shuffle tree / no LN epilogue.
// loads + bf16 pack->LDS + MFMA + stores (garbage values; overwritten later).
// ===========================================================================
__launch_bounds__(256)
__global__ void kA_nostats(const float* __restrict__ inp, const __bf16* __restrict__ WTf,
                           __bf16* __restrict__ keys, __bf16* __restrict__ valsT) {
  __shared__ __bf16 Xs[4][16][136];
  const int tid = threadIdx.x, wave = tid >> 6, lane = tid & 63;
  const int half = lane >> 5, hl = lane & 31;
  const int t = lane & 15, g = lane >> 4;
  const int rbase = blockIdx.x * 64 + wave * 16;

  float4 xr[8];
#pragma unroll
  for (int p = 0; p < 8; ++p)
    xr[p] = *(const float4*)(inp + (size_t)(rbase + 2 * p + half) * DIN + hl * 4);
#pragma unroll
  for (int p = 0; p < 8; ++p) {
    union { ushort4 u; __bf16 h[4]; } pk;
    pk.h[0] = (__bf16)xr[p].x; pk.h[1] = (__bf16)xr[p].y;
    pk.h[2] = (__bf16)xr[p].z; pk.h[3] = (__bf16)xr[p].w;
    *(ushort4*)&Xs[wave][2 * p + half][hl * 4] = pk.u;
  }
  const bf16x8* __restrict__ Wv8 = (const bf16x8*)WTf;
  f32x4 acc[8] = {};
#pragma unroll
  for (int ks = 0; ks < 4; ++ks) {
    const bf16x8 xf = *(const bf16x8*)&Xs[wave][t][ks * 32 + g * 8];
#pragma unroll
    for (int nt = 0; nt < 8; ++nt) {
      const bf16x8 wf = Wv8[(ks * 8 + nt) * 64 + lane];
      acc[nt] = __builtin_amdgcn_mfma_f32_16x16x32_bf16(wf, xf, acc[nt], 0, 0, 0);
    }
  }
  const int bidx = rbase >> 12;
  const int tIB  = (rbase & 4095) + t;
#pragma unroll
  for (int nt = 0; nt < 8; ++nt) {
    if (nt < 4) {
      union { unsigned long long u; __bf16 h[4]; } pk;
      pk.h[0] = (__bf16)acc[nt][0]; pk.h[1] = (__bf16)acc[nt][1];
      pk.h[2] = (__bf16)acc[nt][2]; pk.h[3] = (__bf16)acc[nt][3];
      *(unsigned long long*)&keys[(size_t)(rbase + t) * 64 + nt * 16 + g * 4] = pk.u;
    } else {
      const int vc = (nt - 4) * 16 + g * 4;
#pragma unroll
      for (int r = 0; r < 4; ++r)
        valsT[((size_t)bidx * 64 + vc + r) * NTOK + tIB] = (__bf16)acc[nt][r];
    }
  }
}

// ===========================================================================
// ABLATION VARIANT B: full compute, NO global stores (asm keep-alive).
// ===========================================================================
__launch_bounds__(256)
__global__ void kB_nostores(const float* __restrict__ inp, const __bf16* __restrict__ WTf,
                            const float* __restrict__ EP) {
  __shared__ __bf16 Xs[4][16][136];
  __shared__ float rowstats[4][16][2];
  const int tid = threadIdx.x, wave = tid >> 6, lane = tid & 63;
  const int half = lane >> 5, hl = lane & 31;
  const int t = lane & 15, g = lane >> 4;
  const int rbase = blockIdx.x * 64 + wave * 16;

  float4 xr[8];
#pragma unroll
  for (int p = 0; p < 8; ++p)
    xr[p] = *(const float4*)(inp + (size_t)(rbase + 2 * p + half) * DIN + hl * 4);

  float s[8], sq[8];
#pragma unroll
  for (int p = 0; p < 8; ++p) {
    s[p]  = xr[p].x + xr[p].y + xr[p].z + xr[p].w;
    sq[p] = xr[p].x * xr[p].x + xr[p].y * xr[p].y + xr[p].z * xr[p].z + xr[p].w * xr[p].w;
    union { ushort4 u; __bf16 h[4]; } pk;
    pk.h[0] = (__bf16)xr[p].x; pk.h[1] = (__bf16)xr[p].y;
    pk.h[2] = (__bf16)xr[p].z; pk.h[3] = (__bf16)xr[p].w;
    *(ushort4*)&Xs[wave][2 * p + half][hl * 4] = pk.u;
  }
#pragma unroll
  for (int o = 16; o > 0; o >>= 1) {
#pragma unroll
    for (int p = 0; p < 8; ++p) { s[p] += __shfl_xor(s[p], o); sq[p] += __shfl_xor(sq[p], o); }
  }
  if (hl < 8) {
    const int p = hl;
    const float m = s[p] * (1.f / 128.f);
    const float rstd = rsqrtf(sq[p] * (1.f / 128.f) - m * m + LN_EPS);
    rowstats[wave][2 * p + half][0] = m;
    rowstats[wave][2 * p + half][1] = rstd;
  }
  const bf16x8* __restrict__ Wv8 = (const bf16x8*)WTf;
  f32x4 acc[8] = {};
#pragma unroll
  for (int ks = 0; ks < 4; ++ks) {
    const bf16x8 xf = *(const bf16x8*)&Xs[wave][t][ks * 32 + g * 8];
#pragma unroll
    for (int nt = 0; nt < 8; ++nt) {
      const bf16x8 wf = Wv8[(ks * 8 + nt) * 64 + lane];
      acc[nt] = __builtin_amdgcn_mfma_f32_16x16x32_bf16(wf, xf, acc[nt], 0, 0, 0);
    }
  }
  const float2 mrs = *(const float2*)&rowstats[wave][t][0];
  const float rstd = mrs.y, mm = mrs.x * mrs.y;
#pragma unroll
  for (int nt = 0; nt < 8; ++nt) {
    const float4 Gv = *(const float4*)(EP + nt * 16 + g * 4);
    const float4 Bv = *(const float4*)(EP + 128 + nt * 16 + g * 4);
    const float o0 = rstd * acc[nt][0] - mm * Gv.x + Bv.x;
    const float o1 = rstd * acc[nt][1] - mm * Gv.y + Bv.y;
    const float o2 = rstd * acc[nt][2] - mm * Gv.z + Bv.z;
    const float o3 = rstd * acc[nt][3] - mm * Gv.w + Bv.w;
    asm volatile("" :: "v"(o0), "v"(o1), "v"(o2), "v"(o3));   // keep alive, no store
  }
}

// ===========================================================================
// ABLATION VARIANT C: no MFMA / no WTf reads. loads + stats + epilogue stores.
// ===========================================================================
__launch_bounds__(256)
__global__ void kC_nomfma(const float* __restrict__ inp, const float* __restrict__ EP,
                          __bf16* __restrict__ keys, __bf16* __restrict__ valsT) {
  __shared__ float rowstats[4][16][2];
  const int tid = threadIdx.x, wave = tid >> 6, lane = tid & 63;
  const int half = lane >> 5, hl = lane & 31;
  const int t = lane & 15, g = lane >> 4;
  const int rbase = blockIdx.x * 64 + wave * 16;

  float4 xr[8];
#pragma unroll
  for (int p = 0; p < 8; ++p)
    xr[p] = *(const float4*)(inp + (size_t)(rbase + 2 * p + half) * DIN + hl * 4);

  float s[8], sq[8];
#pragma unroll
  for (int p = 0; p < 8; ++p) {
    s[p]  = xr[p].x + xr[p].y + xr[p].z + xr[p].w;
    sq[p] = xr[p].x * xr[p].x + xr[p].y * xr[p].y + xr[p].z * xr[p].z + xr[p].w * xr[p].w;
  }
#pragma unroll
  for (int o = 16; o > 0; o >>= 1) {
#pragma unroll
    for (int p = 0; p < 8; ++p) { s[p] += __shfl_xor(s[p], o); sq[p] += __shfl_xor(sq[p], o); }
  }
  if (hl < 8) {
    const int p = hl;
    const float m = s[p] * (1.f / 128.f);
    const float rstd = rsqrtf(sq[p] * (1.f / 128.f) - m * m + LN_EPS);
    rowstats[wave][2 * p + half][0] = m;
    rowstats[wave][2 * p + half][1] = rstd;
  }
  __builtin_amdgcn_s_barrier();
  const float2 mrs = *(const float2*)&rowstats[wave][t][0];
  const float rstd = mrs.y, mm = mrs.x * mrs.y;
  const int bidx = rbase >> 12;
  const int tIB  = (rbase & 4095) + t;
#pragma unroll
  for (int nt = 0; nt < 8; ++nt) {
    const float4 Gv = *(const float4*)(EP + nt * 16 + g * 4);
    const float4 Bv = *(const float4*)(EP + 128 + nt * 16 + g * 4);
    const float o0 = -mm * Gv.x + Bv.x + rstd;
    const float o1 = -mm * Gv.y + Bv.y + rstd;
    const float o2 = -mm * Gv.z + Bv.z + rstd;
    const float o3 = -mm * Gv.w + Bv.w + rstd;
    if (nt < 4) {
      union { unsigned long long u; __bf16 h[4]; } pk;
      pk.h[0] = (__bf16)o0; pk.h[1] = (__bf16)o1; pk.h[2] = (__bf16)o2; pk.h[3] = (__bf16)o3;
      *(unsigned long long*)&keys[(size_t)(rbase + t) * 64 + nt * 16 + g * 4] = pk.u;
    } else {
      const int vc = (nt - 4) * 16 + g * 4;
      valsT[((size_t)bidx * 64 + vc + 0) * NTOK + tIB] = (__bf16)o0;
      valsT[((size_t)bidx * 64 + vc + 1) * NTOK + tIB] = (__bf16)o1;
      valsT[((size_t)bidx * 64 + vc + 2) * NTOK + tIB] = (__bf16)o2;
      valsT[((size_t)bidx * 64 + vc + 3) * NTOK + tIB] = (__bf16)o3;
    }
  }
}

// ---------------------------------------------------------------------------
// Kernel 1 (REAL, r5 body): fused LN+projection, LN folded into epilogue.
// ---------------------------------------------------------------------------
__launch_bounds__(256)
__global__ void k_lnproj(const float* __restrict__ inp, const __bf16* __restrict__ WTf,
                         const float* __restrict__ EP, __bf16* __restrict__ keys,
                         __bf16* __restrict__ valsT) {
  __shared__ __bf16 Xs[4][16][136];
  __shared__ float rowstats[4][16][2];
  const int tid = threadIdx.x, wave = tid >> 6, lane = tid & 63;
  const int half = lane >> 5, hl = lane & 31;
  const int t = lane & 15, g = lane >> 4;
  const int rbase = blockIdx.x * 64 + wave * 16;

  float4 xr[8];
#pragma unroll
  for (int p = 0; p < 8; ++p)
    xr[p] = *(const float4*)(inp + (size_t)(rbase + 2 * p + half) * DIN + hl * 4);

  float s[8], sq[8];
#pragma unroll
  for (int p = 0; p < 8; ++p) {
    s[p]  = xr[p].x + xr[p].y + xr[p].z + xr[p].w;
    sq[p] = xr[p].x * xr[p].x + xr[p].y * xr[p].y + xr[p].z * xr[p].z + xr[p].w * xr[p].w;
    union { ushort4 u; __bf16 h[4]; } pk;
    pk.h[0] = (__bf16)xr[p].x; pk.h[1] = (__bf16)xr[p].y;
    pk.h[2] = (__bf16)xr[p].z; pk.h[3] = (__bf16)xr[p].w;
    *(ushort4*)&Xs[wave][2 * p + half][hl * 4] = pk.u;
  }
#pragma unroll
  for (int o = 16; o > 0; o >>= 1) {
#pragma unroll
    for (int p = 0; p < 8; ++p) { s[p] += __shfl_xor(s[p], o); sq[p] += __shfl_xor(sq[p], o); }
  }
  if (hl < 8) {
    const int p = hl;
    const float m = s[p] * (1.f / 128.f);
    const float rstd = rsqrtf(sq[p] * (1.f / 128.f) - m * m + LN_EPS);
    rowstats[wave][2 * p + half][0] = m;
    rowstats[wave][2 * p + half][1] = rstd;
  }
  const bf16x8* __restrict__ Wv8 = (const bf16x8*)WTf;
  f32x4 acc[8] = {};
#pragma unroll
  for (int ks = 0; ks < 4; ++ks) {
    const bf16x8 xf = *(const bf16x8*)&Xs[wave][t][ks * 32 + g * 8];
#pragma unroll
    for (int nt = 0; nt < 8; ++nt) {
      const bf16x8 wf = Wv8[(ks * 8 + nt) * 64 + lane];
      acc[nt] = __builtin_amdgcn_mfma_f32_16x16x32_bf16(wf, xf, acc[nt], 0, 0, 0);
    }
  }
  const float2 mrs = *(const float2*)&rowstats[wave][t][0];
  const float rstd = mrs.y, mm = mrs.x * mrs.y;
  const int bidx = rbase >> 12;
  const int tIB  = (rbase & 4095) + t;
#pragma unroll
  for (int nt = 0; nt < 8; ++nt) {
    const float4 Gv = *(const float4*)(EP + nt * 16 + g * 4);
    const float4 Bv = *(const float4*)(EP + 128 + nt * 16 + g * 4);
    const float o0 = rstd * acc[nt][0] - mm * Gv.x + Bv.x;
    const float o1 = rstd * acc[nt][1] - mm * Gv.y + Bv.y;
    const float o2 = rstd * acc[nt][2] - mm * Gv.z + Bv.z;
    const float o3 = rstd * acc[nt][3] - mm * Gv.w + Bv.w;
    if (nt < 4) {
      union { unsigned long long u; __bf16 h[4]; } pk;
      pk.h[0] = (__bf16)o0; pk.h[1] = (__bf16)o1; pk.h[2] = (__bf16)o2; pk.h[3] = (__bf16)o3;
      *(unsigned long long*)&keys[(size_t)(rbase + t) * 64 + nt * 16 + g * 4] = pk.u;
    } else {
      const int vc = (nt - 4) * 16 + g * 4;
      valsT[((size_t)bidx * 64 + vc + 0) * NTOK + tIB] = (__bf16)o0;
      valsT[((size_t)bidx * 64 + vc + 1) * NTOK + tIB] = (__bf16)o1;
      valsT[((size_t)bidx * 64 + vc + 2) * NTOK + tIB] = (__bf16)o2;
      valsT[((size_t)bidx * 64 + vc + 3) * NTOK + tIB] = (__bf16)o3;
    }
  }
}

// ---------------------------------------------------------------------------
// Kernel 2: slots = broadcast(init_latents); q = SCALE·(LN_q(slots) @ Wq)
// ---------------------------------------------------------------------------
__global__ void k_init(const float* __restrict__ init_lat, const float* __restrict__ qg,
                       const float* __restrict__ qb, const float* __restrict__ Wq,
                       float* __restrict__ slots, float* __restrict__ q) {
  const int b = blockIdx.x;
  const int k = threadIdx.x >> 6, c = threadIdx.x & 63;
  const float s = init_lat[k * DSL + c];
  slots[(size_t)(b * KSL + k) * DSL + c] = s;
  float sum = s, sq = s * s;
#pragma unroll
  for (int o = 32; o > 0; o >>= 1) { sum += __shfl_xor(sum, o); sq += __shfl_xor(sq, o); }
  const float m = sum * (1.f / 64.f);
  const float rstd = rsqrtf(sq * (1.f / 64.f) - m * m + LN_EPS);
  const float qn = (s - m) * rstd * qg[c] + qb[c];
  float acc = 0.f;
  for (int i = 0; i < DSL; ++i) acc += __shfl(qn, i) * Wq[i * DSL + c];
  q[(size_t)(b * KSL + k) * DSL + c] = acc * SCALE;
}

// ---------------------------------------------------------------------------
// Kernel 3: attention via MFMA. 4 waves/block, each wave = 128 tokens.
// ---------------------------------------------------------------------------
__launch_bounds__(256)
__global__ void k_attn(const __bf16* __restrict__ keys, const __bf16* __restrict__ valsT,
                       const float* __restrict__ q, float* __restrict__ Upart,
                       float* __restrict__ Spart, float* __restrict__ attn_out) {
  __shared__ __bf16 P[4][2][16][72];
  const int wave = threadIdx.x >> 6, lane = threadIdx.x & 63;
  const int gid = blockIdx.x * 4 + wave;
  const int b = gid >> 5, sp = gid & 31;
  const int g = lane >> 4, t = lane & 15;

  bf16x8 qf[2];
#pragma unroll
  for (int ks = 0; ks < 2; ++ks) {
    float4 q0 = {0.f, 0.f, 0.f, 0.f}, q1 = {0.f, 0.f, 0.f, 0.f};
    if (t < KSL) {
      const float* __restrict__ qp = q + (size_t)(b * KSL + t) * DSL + ks * 32 + g * 8;
      q0 = *(const float4*)qp; q1 = *(const float4*)(qp + 4);
    }
    qf[ks][0] = (__bf16)q0.x; qf[ks][1] = (__bf16)q0.y;
    qf[ks][2] = (__bf16)q0.z; qf[ks][3] = (__bf16)q0.w;
    qf[ks][4] = (__bf16)q1.x; qf[ks][5] = (__bf16)q1.y;
    qf[ks][6] = (__bf16)q1.z; qf[ks][7] = (__bf16)q1.w;
  }

  const __bf16* __restrict__ kbase = keys + ((size_t)b * NTOK + sp * 128) * DSL;
  float sacc[4] = {0.f, 0.f, 0.f, 0.f};
  f32x4 U[4] = {};

#pragma unroll
  for (int gr = 0; gr < 2; ++gr) {
    const int tb = gr * 64;
#pragma unroll
    for (int tile = 0; tile < 4; ++tile) {
      f32x4 c = {};
#pragma unroll
      for (int ks = 0; ks < 2; ++ks) {
        const bf16x8 kf = *(const bf16x8*)(kbase + (size_t)(tb + tile * 16 + t) * DSL
                                           + ks * 32 + g * 8);
        c = __builtin_amdgcn_mfma_f32_16x16x32_bf16(qf[ks], kf, c, 0, 0, 0);
      }
      float lg[4];
#pragma unroll
      for (int r = 0; r < 4; ++r)
        lg[r] = (4 * g + r < KSL) ? c[r] : -1e30f;   // q pre-scaled
      float mx = fmaxf(fmaxf(lg[0], lg[1]), fmaxf(lg[2], lg[3]));
      mx = fmaxf(mx, __shfl_xor(mx, 16));
      mx = fmaxf(mx, __shfl_xor(mx, 32));
      float e[4];
#pragma unroll
      for (int r = 0; r < 4; ++r) e[r] = __expf(lg[r] - mx);
      float se = e[0] + e[1] + e[2] + e[3];
      se += __shfl_xor(se, 16);
      se += __shfl_xor(se, 32);
      const float inv = 1.f / se;
#pragma unroll
      for (int r = 0; r < 4; ++r) {
        const float a = e[r] * inv + ATTN_EPS;
        sacc[r] += a;
        P[wave][gr][4 * g + r][tile * 16 + t] = (__bf16)a;
        if (attn_out && 4 * g + r < KSL)
          attn_out[((size_t)b * NTOK + sp * 128 + tb + tile * 16 + t) * KSL + 4 * g + r] = a;
      }
    }
#pragma unroll
    for (int ks = 0; ks < 2; ++ks) {
      const bf16x8 pf = *(const bf16x8*)&P[wave][gr][t][ks * 32 + g * 8];
#pragma unroll
      for (int ct = 0; ct < 4; ++ct) {
        const bf16x8 vf = *(const bf16x8*)(valsT + ((size_t)b * DSL + ct * 16 + t) * NTOK
                                           + sp * 128 + tb + ks * 32 + g * 8);
        U[ct] = __builtin_amdgcn_mfma_f32_16x16x32_bf16(pf, vf, U[ct], 0, 0, 0);
      }
    }
  }

  float* __restrict__ up = Upart + (size_t)(b * NSPLIT + sp) * (KSL * DSL);
#pragma unroll
  for (int ct = 0; ct < 4; ++ct)
#pragma unroll
    for (int r = 0; r < 4; ++r)
      if (4 * g + r < KSL) up[(4 * g + r) * DSL + ct * 16 + t] = U[ct][r];

#pragma unroll
  for (int r = 0; r < 4; ++r) {
#pragma unroll
    for (int o = 1; o < 16; o <<= 1) sacc[r] += __shfl_xor(sacc[r], o);
  }
  if (t == 0) {
    float* __restrict__ spp = Spart + (size_t)(b * NSPLIT + sp) * 16;
#pragma unroll
    for (int r = 0; r < 4; ++r) spp[4 * g + r] = sacc[r];
  }
}

// ---------------------------------------------------------------------------
// Kernel 4: reduce partials -> updates; GRU; LN_f + MLP residual; next q.
// ---------------------------------------------------------------------------
__launch_bounds__(64)
__global__ void k_update(const float* __restrict__ Upart, const float* __restrict__ Spart,
                         float* __restrict__ slots, const float* __restrict__ w_ih,
                         const float* __restrict__ w_hh, const float* __restrict__ b_ih,
                         const float* __restrict__ b_hh, const float* __restrict__ fg,
                         const float* __restrict__ fb, const float* __restrict__ W1,
                         const float* __restrict__ b1v, const float* __restrict__ W2,
                         const float* __restrict__ b2v, const float* __restrict__ qg,
                         const float* __restrict__ qbv, const float* __restrict__ Wq,
                         float* __restrict__ q, float* __restrict__ out_slots) {
  const int row = blockIdx.x;            // 0..703
  const int c = threadIdx.x;
  const int b = row / 11, k = row - b * 11;

  float u = 0.f;
  for (int s = 0; s < NSPLIT; ++s)
    u += Upart[((size_t)(b * NSPLIT + s) * KSL + k) * DSL + c];
  float ss = 0.f;
  for (int s = 0; s < NSPLIT; ++s)
    ss += Spart[(size_t)(b * NSPLIT + s) * 16 + k];
  u /= ss;

  const float h = slots[(size_t)row * DSL + c];

  float gr = b_ih[c], gz = b_ih[64 + c], gn = b_ih[128 + c];
  float hr = b_hh[c], hz = b_hh[64 + c], hn = b_hh[128 + c];
  for (int i = 0; i < 64; ++i) {
    const float ui = __shfl(u, i), hi = __shfl(h, i);
    gr += ui * w_ih[i * 192 + c];       hr += hi * w_hh[i * 192 + c];
    gz += ui * w_ih[i * 192 + 64 + c];  hz += hi * w_hh[i * 192 + 64 + c];
    gn += ui * w_ih[i * 192 + 128 + c]; hn += hi * w_hh[i * 192 + 128 + c];
  }
  const float r = 1.f / (1.f + __expf(-(gr + hr)));
  const float z = 1.f / (1.f + __expf(-(gz + hz)));
  const float nn = tanhf(gn + r * hn);
  float sv = (1.f - z) * nn + z * h;

  float sum = sv, sq = sv * sv;
#pragma unroll
  for (int o = 32; o > 0; o >>= 1) { sum += __shfl_xor(sum, o); sq += __shfl_xor(sq, o); }
  float m = sum * (1.f / 64.f);
  float rstd = rsqrtf(sq * (1.f / 64.f) - m * m + LN_EPS);
  const float sl = (sv - m) * rstd * fg[c] + fb[c];

  float h0 = b1v[c], h1 = b1v[64 + c], h2 = b1v[128 + c], h3 = b1v[192 + c];
  for (int i = 0; i < 64; ++i) {
    const float si = __shfl(sl, i);
    h0 += si * W1[i * 256 + c];        h1 += si * W1[i * 256 + 64 + c];
    h2 += si * W1[i * 256 + 128 + c];  h3 += si * W1[i * 256 + 192 + c];
  }
  h0 = fmaxf(h0, 0.f); h1 = fmaxf(h1, 0.f); h2 = fmaxf(h2, 0.f); h3 = fmaxf(h3, 0.f);

  float o = b2v[c];
  for (int j = 0; j < 64; ++j) o += __shfl(h0, j) * W2[j * DSL + c];
  for (int j = 0; j < 64; ++j) o += __shfl(h1, j) * W2[(64 + j) * DSL + c];
  for (int j = 0; j < 64; ++j) o += __shfl(h2, j) * W2[(128 + j) * DSL + c];
  for (int j = 0; j < 64; ++j) o += __shfl(h3, j) * W2[(192 + j) * DSL + c];
  sv += o;

  slots[(size_t)row * DSL + c] = sv;
  if (out_slots) out_slots[(size_t)row * DSL + c] = sv;

  float s2 = sv, q2 = sv * sv;
#pragma unroll
  for (int o2 = 32; o2 > 0; o2 >>= 1) { s2 += __shfl_xor(s2, o2); q2 += __shfl_xor(q2, o2); }
  m = s2 * (1.f / 64.f);
  rstd = rsqrtf(q2 * (1.f / 64.f) - m * m + LN_EPS);
  const float qn = (sv - m) * rstd * qg[c] + qbv[c];
  float qa = 0.f;
  for (int i = 0; i < 64; ++i) qa += __shfl(qn, i) * Wq[i * DSL + c];
  q[(size_t)row * DSL + c] = qa * SCALE;
}

// ---------------------------------------------------------------------------
extern "C" void kernel_launch(void* const* d_in, const int* in_sizes, int n_in,
                              void* d_out, int out_size, void* d_ws, size_t ws_size,
                              hipStream_t stream) {
  const float* inp  = (const float*)d_in[0];
  const float* lng  = (const float*)d_in[1];
  const float* lnb  = (const float*)d_in[2];
  const float* Wk   = (const float*)d_in[3];
  const float* Wv   = (const float*)d_in[4];
  const float* init = (const float*)d_in[5];
  const float* qg   = (const float*)d_in[6];
  const float* qbb  = (const float*)d_in[7];
  const float* Wq   = (const float*)d_in[8];
  const float* wih  = (const float*)d_in[9];
  const float* whh  = (const float*)d_in[10];
  const float* bih  = (const float*)d_in[11];
  const float* bhh  = (const float*)d_in[12];
  const float* fg   = (const float*)d_in[13];
  const float* fb   = (const float*)d_in[14];
  const float* W1   = (const float*)d_in[15];
  const float* b1   = (const float*)d_in[16];
  const float* W2   = (const float*)d_in[17];
  const float* b2   = (const float*)d_in[18];

  char* wsb = (char*)d_ws;
  __bf16* keys  = (__bf16*)wsb;                                  // 33.55 MB
  __bf16* valsT = keys + (size_t)NB * NTOK * DSL;                // 33.55 MB
  __bf16* WTf   = valsT + (size_t)NB * DSL * NTOK;               // 32 KB
  float*  EP    = (float*)(WTf + 16384);                         // 1 KB
  float* slots = EP + 256;
  float* q     = slots + NB * KSL * DSL;
  float* Upart = q + NB * KSL * DSL;                             // 5.77 MB
  float* Spart = Upart + (size_t)NB * NSPLIT * KSL * DSL;        // 128 KB

  float* out_slots = (float*)d_out;
  float* out_attn  = (float*)d_out + NB * KSL * DSL;

  k_prep<<<9, 256, 0, stream>>>(Wk, Wv, lng, lnb, WTf, EP);
  // ---- ablation variants (diagnostic; outputs overwritten by real pass) ----
  kA_nostats<<<4096, 256, 0, stream>>>(inp, WTf, keys, valsT);
  kB_nostores<<<4096, 256, 0, stream>>>(inp, WTf, EP);
  kC_nomfma<<<4096, 256, 0, stream>>>(inp, EP, keys, valsT);
  // ---- real pass ----
  k_lnproj<<<4096, 256, 0, stream>>>(inp, WTf, EP, keys, valsT);
  k_init<<<NB, KSL * 64, 0, stream>>>(init, qg, qbb, Wq, slots, q);
  for (int t = 0; t < 3; ++t) {
    k_attn<<<512, 256, 0, stream>>>(keys, valsT, q, Upart, Spart,
                                    t == 2 ? out_attn : nullptr);
    k_update<<<NB * KSL, 64, 0, stream>>>(Upart, Spart, slots, wih, whh, bih, bhh,
                                          fg, fb, W1, b1, W2, b2, qg, qbb, Wq, q,
                                          t == 2 ? out_slots : nullptr);
  }
}

// Round 9
// 152.885 us; speedup vs baseline: 1.9108x; 1.9108x over previous
//
#include <hip/hip_runtime.h>

#define DIN   128
#define DSL   64
#define KSL   11
#define NTOK  4096
#define NB    64
#define NSPLIT 32
#define LN_EPS   1e-5f
#define ATTN_EPS 1e-8f
#define SCALE    0.125f      // 64^-0.5

typedef __bf16 bf16x8 __attribute__((ext_vector_type(8)));
typedef float  f32x4  __attribute__((ext_vector_type(4)));

// ---------------------------------------------------------------------------
// Kernel 0 (9 blocks): blocks 0..7 pre-gather W' = diag(g)·[Wk|Wv] into MFMA
// A-fragment order; block 8: EP[c] = sum_k g[k]W[k][c], EP[128+c] = b@W.
// ---------------------------------------------------------------------------
__global__ void k_prep(const float* __restrict__ Wk, const float* __restrict__ Wv,
                       const float* __restrict__ g, const float* __restrict__ b,
                       __bf16* __restrict__ WTf, float* __restrict__ EP) {
  if (blockIdx.x == 8) {
    const int c = threadIdx.x;
    if (c < 128) {
      const float* __restrict__ W = (c < 64) ? Wk : Wv;
      const int cc = c & 63;
      float G = 0.f, Bt = 0.f;
      for (int k = 0; k < 128; ++k) {
        const float w = W[k * 64 + cc];
        G += g[k] * w; Bt += b[k] * w;
      }
      EP[c] = G; EP[128 + c] = Bt;
    }
    return;
  }
  const int t = blockIdx.x * 256 + threadIdx.x;
  const int fid = t >> 6, lane = t & 63;
  const int ks = fid >> 3, nt = fid & 7;
  const int col = nt * 16 + (lane & 15);
  const int kb  = ks * 32 + (lane >> 4) * 8;
  union { uint4 u; __bf16 h[8]; } o;
#pragma unroll
  for (int j = 0; j < 8; ++j) {
    const int k = kb + j;
    const float v = ((col < 64) ? Wk[k * 64 + col] : Wv[k * 64 + (col - 64)]) * g[k];
    o.h[j] = (__bf16)v;
  }
  *((uint4*)WTf + t) = o.u;
}

// ---------------------------------------------------------------------------
// Kernel 1 (r5 body): fused LN+projection, LN folded into epilogue.
// Cold-read bound at ~80 µs (r8 ablation: structure-invariant input floor).
// ---------------------------------------------------------------------------
__launch_bounds__(256)
__global__ void k_lnproj(const float* __restrict__ inp, const __bf16* __restrict__ WTf,
                         const float* __restrict__ EP, __bf16* __restrict__ keys,
                         __bf16* __restrict__ valsT) {
  __shared__ __bf16 Xs[4][16][136];
  __shared__ float rowstats[4][16][2];
  const int tid = threadIdx.x, wave = tid >> 6, lane = tid & 63;
  const int half = lane >> 5, hl = lane & 31;
  const int t = lane & 15, g = lane >> 4;
  const int rbase = blockIdx.x * 64 + wave * 16;

  float4 xr[8];
#pragma unroll
  for (int p = 0; p < 8; ++p)
    xr[p] = *(const float4*)(inp + (size_t)(rbase + 2 * p + half) * DIN + hl * 4);

  float s[8], sq[8];
#pragma unroll
  for (int p = 0; p < 8; ++p) {
    s[p]  = xr[p].x + xr[p].y + xr[p].z + xr[p].w;
    sq[p] = xr[p].x * xr[p].x + xr[p].y * xr[p].y + xr[p].z * xr[p].z + xr[p].w * xr[p].w;
    union { ushort4 u; __bf16 h[4]; } pk;
    pk.h[0] = (__bf16)xr[p].x; pk.h[1] = (__bf16)xr[p].y;
    pk.h[2] = (__bf16)xr[p].z; pk.h[3] = (__bf16)xr[p].w;
    *(ushort4*)&Xs[wave][2 * p + half][hl * 4] = pk.u;
  }
#pragma unroll
  for (int o = 16; o > 0; o >>= 1) {
#pragma unroll
    for (int p = 0; p < 8; ++p) { s[p] += __shfl_xor(s[p], o); sq[p] += __shfl_xor(sq[p], o); }
  }
  if (hl < 8) {
    const int p = hl;
    const float m = s[p] * (1.f / 128.f);
    const float rstd = rsqrtf(sq[p] * (1.f / 128.f) - m * m + LN_EPS);
    rowstats[wave][2 * p + half][0] = m;
    rowstats[wave][2 * p + half][1] = rstd;
  }
  const bf16x8* __restrict__ Wv8 = (const bf16x8*)WTf;
  f32x4 acc[8] = {};
#pragma unroll
  for (int ks = 0; ks < 4; ++ks) {
    const bf16x8 xf = *(const bf16x8*)&Xs[wave][t][ks * 32 + g * 8];
#pragma unroll
    for (int nt = 0; nt < 8; ++nt) {
      const bf16x8 wf = Wv8[(ks * 8 + nt) * 64 + lane];
      acc[nt] = __builtin_amdgcn_mfma_f32_16x16x32_bf16(wf, xf, acc[nt], 0, 0, 0);
    }
  }
  const float2 mrs = *(const float2*)&rowstats[wave][t][0];
  const float rstd = mrs.y, mm = mrs.x * mrs.y;
  const int bidx = rbase >> 12;
  const int tIB  = (rbase & 4095) + t;
#pragma unroll
  for (int nt = 0; nt < 8; ++nt) {
    const float4 Gv = *(const float4*)(EP + nt * 16 + g * 4);
    const float4 Bv = *(const float4*)(EP + 128 + nt * 16 + g * 4);
    const float o0 = rstd * acc[nt][0] - mm * Gv.x + Bv.x;
    const float o1 = rstd * acc[nt][1] - mm * Gv.y + Bv.y;
    const float o2 = rstd * acc[nt][2] - mm * Gv.z + Bv.z;
    const float o3 = rstd * acc[nt][3] - mm * Gv.w + Bv.w;
    if (nt < 4) {
      union { unsigned long long u; __bf16 h[4]; } pk;
      pk.h[0] = (__bf16)o0; pk.h[1] = (__bf16)o1; pk.h[2] = (__bf16)o2; pk.h[3] = (__bf16)o3;
      *(unsigned long long*)&keys[(size_t)(rbase + t) * 64 + nt * 16 + g * 4] = pk.u;
    } else {
      const int vc = (nt - 4) * 16 + g * 4;
      valsT[((size_t)bidx * 64 + vc + 0) * NTOK + tIB] = (__bf16)o0;
      valsT[((size_t)bidx * 64 + vc + 1) * NTOK + tIB] = (__bf16)o1;
      valsT[((size_t)bidx * 64 + vc + 2) * NTOK + tIB] = (__bf16)o2;
      valsT[((size_t)bidx * 64 + vc + 3) * NTOK + tIB] = (__bf16)o3;
    }
  }
}

// ---------------------------------------------------------------------------
// Kernel 2: slots = broadcast(init_latents); q = SCALE·(LN_q(slots) @ Wq)
// ---------------------------------------------------------------------------
__global__ void k_init(const float* __restrict__ init_lat, const float* __restrict__ qg,
                       const float* __restrict__ qb, const float* __restrict__ Wq,
                       float* __restrict__ slots, float* __restrict__ q) {
  const int b = blockIdx.x;
  const int k = threadIdx.x >> 6, c = threadIdx.x & 63;
  const float s = init_lat[k * DSL + c];
  slots[(size_t)(b * KSL + k) * DSL + c] = s;
  float sum = s, sq = s * s;
#pragma unroll
  for (int o = 32; o > 0; o >>= 1) { sum += __shfl_xor(sum, o); sq += __shfl_xor(sq, o); }
  const float m = sum * (1.f / 64.f);
  const float rstd = rsqrtf(sq * (1.f / 64.f) - m * m + LN_EPS);
  const float qn = (s - m) * rstd * qg[c] + qb[c];
  float acc = 0.f;
  for (int i = 0; i < DSL; ++i) acc += __shfl(qn, i) * Wq[i * DSL + c];
  q[(size_t)(b * KSL + k) * DSL + c] = acc * SCALE;
}

// ---------------------------------------------------------------------------
// Kernel 3: attention via MFMA, BATCHED softmax. 1 wave / 128 tokens.
// Per 64-token group: 8 key loads -> 8 QK MFMAs; 8 val loads issued (in
// flight during softmax); 4 tiles' softmax chains interleaved (4-way ILP);
// P -> LDS; 8 PV MFMAs. Deterministic split partials.
// ---------------------------------------------------------------------------
__launch_bounds__(64)
__global__ void k_attn(const __bf16* __restrict__ keys, const __bf16* __restrict__ valsT,
                       const float* __restrict__ q, float* __restrict__ Upart,
                       float* __restrict__ Spart, float* __restrict__ attn_out) {
  __shared__ __bf16 P[2][16][72];
  const int b = blockIdx.x >> 5, sp = blockIdx.x & 31;
  const int lane = threadIdx.x;
  const int g = lane >> 4, t = lane & 15;

  bf16x8 qf[2];
#pragma unroll
  for (int ks = 0; ks < 2; ++ks) {
    float4 q0 = {0.f, 0.f, 0.f, 0.f}, q1 = {0.f, 0.f, 0.f, 0.f};
    if (t < KSL) {
      const float* __restrict__ qp = q + (size_t)(b * KSL + t) * DSL + ks * 32 + g * 8;
      q0 = *(const float4*)qp; q1 = *(const float4*)(qp + 4);
    }
    qf[ks][0] = (__bf16)q0.x; qf[ks][1] = (__bf16)q0.y;
    qf[ks][2] = (__bf16)q0.z; qf[ks][3] = (__bf16)q0.w;
    qf[ks][4] = (__bf16)q1.x; qf[ks][5] = (__bf16)q1.y;
    qf[ks][6] = (__bf16)q1.z; qf[ks][7] = (__bf16)q1.w;
  }

  const __bf16* __restrict__ kbase = keys + ((size_t)b * NTOK + sp * 128) * DSL;
  const __bf16* __restrict__ vbase = valsT + (size_t)b * DSL * NTOK + sp * 128;
  float sacc[4] = {0.f, 0.f, 0.f, 0.f};
  f32x4 U[4] = {};

#pragma unroll
  for (int gr = 0; gr < 2; ++gr) {
    const int tb = gr * 64;
    // ---- all key fragments for this 64-token group ----
    bf16x8 kf[4][2];
#pragma unroll
    for (int tile = 0; tile < 4; ++tile)
#pragma unroll
      for (int ks = 0; ks < 2; ++ks)
        kf[tile][ks] = *(const bf16x8*)(kbase + (size_t)(tb + tile * 16 + t) * DSL
                                        + ks * 32 + g * 8);
    // ---- val fragments issued now (in flight during softmax) ----
    bf16x8 vf[2][4];
#pragma unroll
    for (int ks = 0; ks < 2; ++ks)
#pragma unroll
      for (int ct = 0; ct < 4; ++ct)
        vf[ks][ct] = *(const bf16x8*)(vbase + (size_t)(ct * 16 + t) * NTOK
                                      + tb + ks * 32 + g * 8);
    // ---- QK^T: 8 MFMAs ----
    f32x4 c[4] = {};
#pragma unroll
    for (int ks = 0; ks < 2; ++ks)
#pragma unroll
      for (int tile = 0; tile < 4; ++tile)
        c[tile] = __builtin_amdgcn_mfma_f32_16x16x32_bf16(qf[ks], kf[tile][ks], c[tile], 0, 0, 0);
    // ---- batched softmax: 4 independent chains interleaved ----
    float lg[4][4], mx[4];
#pragma unroll
    for (int tile = 0; tile < 4; ++tile) {
#pragma unroll
      for (int r = 0; r < 4; ++r)
        lg[tile][r] = (4 * g + r < KSL) ? c[tile][r] : -1e30f;   // q pre-scaled
      mx[tile] = fmaxf(fmaxf(lg[tile][0], lg[tile][1]), fmaxf(lg[tile][2], lg[tile][3]));
    }
#pragma unroll
    for (int tile = 0; tile < 4; ++tile) mx[tile] = fmaxf(mx[tile], __shfl_xor(mx[tile], 16));
#pragma unroll
    for (int tile = 0; tile < 4; ++tile) mx[tile] = fmaxf(mx[tile], __shfl_xor(mx[tile], 32));
    float se[4];
#pragma unroll
    for (int tile = 0; tile < 4; ++tile) {
#pragma unroll
      for (int r = 0; r < 4; ++r) lg[tile][r] = __expf(lg[tile][r] - mx[tile]);
      se[tile] = lg[tile][0] + lg[tile][1] + lg[tile][2] + lg[tile][3];
    }
#pragma unroll
    for (int tile = 0; tile < 4; ++tile) se[tile] += __shfl_xor(se[tile], 16);
#pragma unroll
    for (int tile = 0; tile < 4; ++tile) se[tile] += __shfl_xor(se[tile], 32);
#pragma unroll
    for (int tile = 0; tile < 4; ++tile) {
      const float inv = 1.f / se[tile];
#pragma unroll
      for (int r = 0; r < 4; ++r) {
        const float a = lg[tile][r] * inv + ATTN_EPS;
        sacc[r] += a;
        P[gr][4 * g + r][tile * 16 + t] = (__bf16)a;
        if (attn_out && 4 * g + r < KSL)
          attn_out[((size_t)b * NTOK + sp * 128 + tb + tile * 16 + t) * KSL + 4 * g + r] = a;
      }
    }
    // ---- PV: 8 MFMAs (vals already in registers) ----
#pragma unroll
    for (int ks = 0; ks < 2; ++ks) {
      const bf16x8 pf = *(const bf16x8*)&P[gr][t][ks * 32 + g * 8];
#pragma unroll
      for (int ct = 0; ct < 4; ++ct)
        U[ct] = __builtin_amdgcn_mfma_f32_16x16x32_bf16(pf, vf[ks][ct], U[ct], 0, 0, 0);
    }
  }

  float* __restrict__ up = Upart + (size_t)(b * NSPLIT + sp) * (KSL * DSL);
#pragma unroll
  for (int ct = 0; ct < 4; ++ct)
#pragma unroll
    for (int r = 0; r < 4; ++r)
      if (4 * g + r < KSL) up[(4 * g + r) * DSL + ct * 16 + t] = U[ct][r];

#pragma unroll
  for (int r = 0; r < 4; ++r) {
#pragma unroll
    for (int o = 1; o < 16; o <<= 1) sacc[r] += __shfl_xor(sacc[r], o);
  }
  if (t == 0) {
    float* __restrict__ spp = Spart + (size_t)(b * NSPLIT + sp) * 16;
#pragma unroll
    for (int r = 0; r < 4; ++r) spp[4 * g + r] = sacc[r];
  }
}

// ---------------------------------------------------------------------------
// Kernel 4: reduce -> GRU -> LN_f + MLP residual -> next q.
// 704 blocks x 128 threads: TWO waves per row, every long i-loop split
// across waves with LDS partial-reduce (disjoint LDS per stage).
// ---------------------------------------------------------------------------
__launch_bounds__(128)
__global__ void k_update(const float* __restrict__ Upart, const float* __restrict__ Spart,
                         float* __restrict__ slots, const float* __restrict__ w_ih,
                         const float* __restrict__ w_hh, const float* __restrict__ b_ih,
                         const float* __restrict__ b_hh, const float* __restrict__ fg,
                         const float* __restrict__ fb, const float* __restrict__ W1,
                         const float* __restrict__ b1v, const float* __restrict__ W2,
                         const float* __restrict__ b2v, const float* __restrict__ qg,
                         const float* __restrict__ qbv, const float* __restrict__ Wq,
                         float* __restrict__ q, float* __restrict__ out_slots) {
  __shared__ float rU[2][64];
  __shared__ float rS[2];
  __shared__ float rG[2][6][64];
  __shared__ float rH[2][4][64];
  __shared__ float rO[2][64];
  __shared__ float rQ[2][64];
  const int w = threadIdx.x >> 6, c = threadIdx.x & 63;
  const int row = blockIdx.x;            // 0..703
  const int b = row / 11, k = row - b * 11;

  // ---- stage 1: Upart/Spart reduce (split 16/16) ----
  float upi = 0.f, ssp = 0.f;
  for (int s = w * 16; s < w * 16 + 16; ++s) {
    upi += Upart[((size_t)(b * NSPLIT + s) * KSL + k) * DSL + c];
    ssp += Spart[(size_t)(b * NSPLIT + s) * 16 + k];
  }
  rU[w][c] = upi;
  if (c == 0) rS[w] = ssp;
  const float h = slots[(size_t)row * DSL + c];
  __syncthreads();
  const float u = (rU[0][c] + rU[1][c]) / (rS[0] + rS[1]);

  // ---- stage 2: GRU gates (i-loop split 32/32) ----
  float gr = 0.f, gz = 0.f, gn = 0.f, hr = 0.f, hz = 0.f, hn = 0.f;
  for (int i = w * 32; i < w * 32 + 32; ++i) {
    const float ui = __shfl(u, i), hi = __shfl(h, i);
    gr += ui * w_ih[i * 192 + c];       hr += hi * w_hh[i * 192 + c];
    gz += ui * w_ih[i * 192 + 64 + c];  hz += hi * w_hh[i * 192 + 64 + c];
    gn += ui * w_ih[i * 192 + 128 + c]; hn += hi * w_hh[i * 192 + 128 + c];
  }
  rG[w][0][c] = gr; rG[w][1][c] = gz; rG[w][2][c] = gn;
  rG[w][3][c] = hr; rG[w][4][c] = hz; rG[w][5][c] = hn;
  __syncthreads();
  gr = rG[0][0][c] + rG[1][0][c] + b_ih[c];
  gz = rG[0][1][c] + rG[1][1][c] + b_ih[64 + c];
  gn = rG[0][2][c] + rG[1][2][c] + b_ih[128 + c];
  hr = rG[0][3][c] + rG[1][3][c] + b_hh[c];
  hz = rG[0][4][c] + rG[1][4][c] + b_hh[64 + c];
  hn = rG[0][5][c] + rG[1][5][c] + b_hh[128 + c];
  const float r = 1.f / (1.f + __expf(-(gr + hr)));
  const float z = 1.f / (1.f + __expf(-(gz + hz)));
  const float nn = tanhf(gn + r * hn);
  float sv = (1.f - z) * nn + z * h;

  // ---- LN_f (both waves, identical data) ----
  float sum = sv, sq = sv * sv;
#pragma unroll
  for (int o = 32; o > 0; o >>= 1) { sum += __shfl_xor(sum, o); sq += __shfl_xor(sq, o); }
  float m = sum * (1.f / 64.f);
  float rstd = rsqrtf(sq * (1.f / 64.f) - m * m + LN_EPS);
  const float sl = (sv - m) * rstd * fg[c] + fb[c];

  // ---- stage 3: W1 (i-loop split 32/32) ----
  float h0 = 0.f, h1 = 0.f, h2 = 0.f, h3 = 0.f;
  for (int i = w * 32; i < w * 32 + 32; ++i) {
    const float si = __shfl(sl, i);
    h0 += si * W1[i * 256 + c];        h1 += si * W1[i * 256 + 64 + c];
    h2 += si * W1[i * 256 + 128 + c];  h3 += si * W1[i * 256 + 192 + c];
  }
  rH[w][0][c] = h0; rH[w][1][c] = h1; rH[w][2][c] = h2; rH[w][3][c] = h3;
  __syncthreads();
  h0 = fmaxf(rH[0][0][c] + rH[1][0][c] + b1v[c], 0.f);
  h1 = fmaxf(rH[0][1][c] + rH[1][1][c] + b1v[64 + c], 0.f);
  h2 = fmaxf(rH[0][2][c] + rH[1][2][c] + b1v[128 + c], 0.f);
  h3 = fmaxf(rH[0][3][c] + rH[1][3][c] + b1v[192 + c], 0.f);

  // ---- stage 4: W2 (hidden split: wave0 -> h0,h1; wave1 -> h2,h3) ----
  float o = 0.f;
  {
    const float ha = (w == 0) ? h0 : h2;
    const float hb = (w == 0) ? h1 : h3;
    const int base = w * 128;
    for (int j = 0; j < 64; ++j) o += __shfl(ha, j) * W2[(base + j) * DSL + c];
    for (int j = 0; j < 64; ++j) o += __shfl(hb, j) * W2[(base + 64 + j) * DSL + c];
  }
  rO[w][c] = o;
  __syncthreads();
  sv += rO[0][c] + rO[1][c] + b2v[c];

  // ---- q for next iteration (Wq split 32/32) ----
  float s2 = sv, q2 = sv * sv;
#pragma unroll
  for (int o2 = 32; o2 > 0; o2 >>= 1) { s2 += __shfl_xor(s2, o2); q2 += __shfl_xor(q2, o2); }
  m = s2 * (1.f / 64.f);
  rstd = rsqrtf(q2 * (1.f / 64.f) - m * m + LN_EPS);
  const float qn = (sv - m) * rstd * qg[c] + qbv[c];
  float qa = 0.f;
  for (int i = w * 32; i < w * 32 + 32; ++i) qa += __shfl(qn, i) * Wq[i * DSL + c];
  rQ[w][c] = qa;
  __syncthreads();
  if (w == 0) {
    slots[(size_t)row * DSL + c] = sv;
    if (out_slots) out_slots[(size_t)row * DSL + c] = sv;
    q[(size_t)row * DSL + c] = (rQ[0][c] + rQ[1][c]) * SCALE;
  }
}

// ---------------------------------------------------------------------------
extern "C" void kernel_launch(void* const* d_in, const int* in_sizes, int n_in,
                              void* d_out, int out_size, void* d_ws, size_t ws_size,
                              hipStream_t stream) {
  const float* inp  = (const float*)d_in[0];
  const float* lng  = (const float*)d_in[1];
  const float* lnb  = (const float*)d_in[2];
  const float* Wk   = (const float*)d_in[3];
  const float* Wv   = (const float*)d_in[4];
  const float* init = (const float*)d_in[5];
  const float* qg   = (const float*)d_in[6];
  const float* qbb  = (const float*)d_in[7];
  const float* Wq   = (const float*)d_in[8];
  const float* wih  = (const float*)d_in[9];
  const float* whh  = (const float*)d_in[10];
  const float* bih  = (const float*)d_in[11];
  const float* bhh  = (const float*)d_in[12];
  const float* fg   = (const float*)d_in[13];
  const float* fb   = (const float*)d_in[14];
  const float* W1   = (const float*)d_in[15];
  const float* b1   = (const float*)d_in[16];
  const float* W2   = (const float*)d_in[17];
  const float* b2   = (const float*)d_in[18];

  char* wsb = (char*)d_ws;
  __bf16* keys  = (__bf16*)wsb;                                  // 33.55 MB
  __bf16* valsT = keys + (size_t)NB * NTOK * DSL;                // 33.55 MB
  __bf16* WTf   = valsT + (size_t)NB * DSL * NTOK;               // 32 KB
  float*  EP    = (float*)(WTf + 16384);                         // 1 KB
  float* slots = EP + 256;
  float* q     = slots + NB * KSL * DSL;
  float* Upart = q + NB * KSL * DSL;                             // 5.77 MB
  float* Spart = Upart + (size_t)NB * NSPLIT * KSL * DSL;        // 128 KB

  float* out_slots = (float*)d_out;
  float* out_attn  = (float*)d_out + NB * KSL * DSL;

  k_prep<<<9, 256, 0, stream>>>(Wk, Wv, lng, lnb, WTf, EP);
  k_lnproj<<<4096, 256, 0, stream>>>(inp, WTf, EP, keys, valsT);
  k_init<<<NB, KSL * 64, 0, stream>>>(init, qg, qbb, Wq, slots, q);
  for (int t = 0; t < 3; ++t) {
    k_attn<<<NB * NSPLIT, 64, 0, stream>>>(keys, valsT, q, Upart, Spart,
                                           t == 2 ? out_attn : nullptr);
    k_update<<<NB * KSL, 128, 0, stream>>>(Upart, Spart, slots, wih, whh, bih, bhh,
                                           fg, fb, W1, b1, W2, b2, qg, qbb, Wq, q,
                                           t == 2 ? out_slots : nullptr);
  }
}